// Round 10
// baseline (83.615 us; speedup 1.0000x reference)
//
#include <hip/hip_runtime.h>
#include <hip/hip_bf16.h>
#include <stdint.h>

typedef __attribute__((ext_vector_type(4))) float f32x4;
typedef __attribute__((ext_vector_type(8))) short bf16x8;
typedef __attribute__((ext_vector_type(4))) uint32_t u32x4;

#define NCH 21
#define NROW 256
#define DIM 4096
#define BMP 128   // pair-merged tile dim
#define BK 64
#define LDSS 72   // row stride in ushorts: 144 B
#define NTILE 10  // upper-triangle 64x64 tiles of the 256x256 Gram

__device__ const int g_TI[NTILE] = {0, 0, 0, 0, 1, 1, 1, 2, 2, 3};
__device__ const int g_TJ[NTILE] = {0, 1, 2, 3, 1, 2, 3, 2, 3, 3};

__device__ __forceinline__ uint32_t pack_bf2(float x, float y) {
  __hip_bfloat162 h = __float22bfloat162_rn(float2{x, y});  // v_cvt_pk_bf16_f32
  union { __hip_bfloat162 h; uint32_t u; } c;
  c.h = h;
  return c.u;
}

// ---------------------------------------------------------------------------
// Pair-merged partial Gram (R9 geometry) with a real 2-deep pipeline:
//  - TWO named prefetch slots (A/B), main loop unrolled x2 (all reg indices
//    compile-time -> no scratch, rule #20). Loads for iter i+2 are issued at
//    iter i: coverage ~= one full iteration >> HBM latency.
//  - BOTH barriers are lgkmcnt-only raw s_barrier: no vmcnt(0) drain in the
//    loop; vmcnt waits appear only at first register use (T4 discipline).
//    VMEM queue is self-throttled by register WAR on the slot being refilled.
// kchunk is always a multiple of 2*BK (kchunk = 4096/P >= 256), so the x2
// unroll needs no remainder handling.
// ---------------------------------------------------------------------------
struct StageCtx {
  const float* ap[2];
  const float* bp[2];
  bool isdiag;
  int r0, c8, kend;
};

__device__ __forceinline__ void fill_slot(const StageCtx& cx, f32x4 (&va)[2][2],
                                          f32x4 (&vb)[2][2], int k) {
#pragma unroll
  for (int p = 0; p < 2; ++p) {
    va[p][0] = *reinterpret_cast<const f32x4*>(cx.ap[p] + k);
    va[p][1] = *reinterpret_cast<const f32x4*>(cx.ap[p] + k + 4);
    if (!cx.isdiag) {
      vb[p][0] = *reinterpret_cast<const f32x4*>(cx.bp[p] + k);
      vb[p][1] = *reinterpret_cast<const f32x4*>(cx.bp[p] + k + 4);
    }
  }
}

__device__ __forceinline__ void stage_slot(const StageCtx& cx, ushort* As,
                                           ushort* Bs, f32x4 (&va)[2][2],
                                           f32x4 (&vb)[2][2]) {
#pragma unroll
  for (int p = 0; p < 2; ++p) {
    u32x4 wa;
    wa.x = pack_bf2(va[p][0].x, va[p][0].y);
    wa.y = pack_bf2(va[p][0].z, va[p][0].w);
    wa.z = pack_bf2(va[p][1].x, va[p][1].y);
    wa.w = pack_bf2(va[p][1].z, va[p][1].w);
    *reinterpret_cast<u32x4*>(&As[(cx.r0 + p * 64) * LDSS + cx.c8]) = wa;
    if (!cx.isdiag) {
      u32x4 wb;
      wb.x = pack_bf2(vb[p][0].x, vb[p][0].y);
      wb.y = pack_bf2(vb[p][0].z, vb[p][0].w);
      wb.z = pack_bf2(vb[p][1].x, vb[p][1].y);
      wb.w = pack_bf2(vb[p][1].z, vb[p][1].w);
      *reinterpret_cast<u32x4*>(&Bs[(cx.r0 + p * 64) * LDSS + cx.c8]) = wb;
    }
  }
}

__global__ __launch_bounds__(512) void gram_kernel(
    const float* __restrict__ src, const float* __restrict__ tgt,
    float* __restrict__ Gp, int kshift, int kchunk) {
  const int P = 1 << kshift;
  const int NG = NCH << kshift;          // number of (ch,ks) groups
  const int q = NG >> 3, r8 = NG & 7;    // groups per XCD
  const int x = blockIdx.x & 7;          // XCD id (empirical round-robin)
  const int slot = blockIdx.x >> 3;
  const int cnt = q + (x < r8 ? 1 : 0);
  if (slot >= cnt * 3) return;           // padded grid tail (uniform exit)
  const int gbase = (x < r8) ? x * (q + 1) : r8 * (q + 1) + (x - r8) * q;
  const int gi = slot / 3;
  const int bt = slot - gi * 3;
  const int g = gbase + gi;
  const int ch = g >> kshift;
  const int ks = g & (P - 1);
  const int kbase = ks * kchunk;
  const int row_base = (bt == 1) ? 128 : 0;
  const int col_base = (bt == 0) ? 0 : 128;
  const int tid = threadIdx.x;
  const int lane = tid & 63;

  __shared__ __attribute__((aligned(16))) ushort As[BMP * LDSS];
  __shared__ __attribute__((aligned(16))) ushort Bs[BMP * LDSS];

  f32x4 acc[2][4];
#pragma unroll
  for (int m = 0; m < 2; ++m)
#pragma unroll
    for (int n = 0; n < 4; ++n)
      acc[m][n] = (f32x4){0.f, 0.f, 0.f, 0.f};

  const int wave = tid >> 6;          // 0..7
  const int wr = (wave >> 1) * 32;    // 0,32,64,96
  const int wc = (wave & 1) * 64;     // 0,64

  StageCtx cx;
  cx.isdiag = (bt != 2);
  cx.r0 = tid >> 3;          // 0..63
  cx.c8 = (tid & 7) * 8;     // 0,8,...,56
  cx.kend = kbase + kchunk;
  {
    const float* Ab = row_base ? tgt : src;
    const float* Bb = col_base ? tgt : src;
#pragma unroll
    for (int p = 0; p < 2; ++p) {
      cx.ap[p] = Ab + ((size_t)(cx.r0 + p * 64) * NCH + ch) * DIM + cx.c8;
      cx.bp[p] = Bb + ((size_t)(cx.r0 + p * 64) * NCH + ch) * DIM + cx.c8;
    }
  }

  // two named prefetch slots (compile-time indexed -> registers)
  f32x4 vaA[2][2], vbA[2][2], vaB[2][2], vbB[2][2];
  fill_slot(cx, vaA, vbA, kbase);
  fill_slot(cx, vaB, vbB, kbase + BK);

  for (int k0 = kbase; k0 < cx.kend; k0 += 2 * BK) {
    // ---- half-iter A ----
    asm volatile("s_waitcnt lgkmcnt(0)" ::: "memory");  // prev ds_reads done
    __builtin_amdgcn_s_barrier();                        // LDS safe to overwrite
    stage_slot(cx, As, Bs, vaA, vbA);                    // vmcnt wait-at-use here
    if (k0 + 2 * BK < cx.kend) fill_slot(cx, vaA, vbA, k0 + 2 * BK);
    asm volatile("s_waitcnt lgkmcnt(0)" ::: "memory");  // ds_writes visible
    __builtin_amdgcn_s_barrier();
    asm volatile("" ::: "memory");

    {
      const ushort* Bsrc = cx.isdiag ? As : Bs;
#pragma unroll
      for (int kk = 0; kk < 2; ++kk) {
        const int kb = kk * 32 + (lane >> 4) * 8;
        bf16x8 a[2], b[4];
#pragma unroll
        for (int m = 0; m < 2; ++m)
          a[m] = *reinterpret_cast<const bf16x8*>(
              &As[(wr + m * 16 + (lane & 15)) * LDSS + kb]);
#pragma unroll
        for (int n = 0; n < 4; ++n)
          b[n] = *reinterpret_cast<const bf16x8*>(
              &Bsrc[(wc + n * 16 + (lane & 15)) * LDSS + kb]);
#pragma unroll
        for (int m = 0; m < 2; ++m)
#pragma unroll
          for (int n = 0; n < 4; ++n)
            acc[m][n] = __builtin_amdgcn_mfma_f32_16x16x32_bf16(a[m], b[n],
                                                                acc[m][n], 0, 0, 0);
      }
    }

    // ---- half-iter B ----
    asm volatile("s_waitcnt lgkmcnt(0)" ::: "memory");
    __builtin_amdgcn_s_barrier();
    stage_slot(cx, As, Bs, vaB, vbB);
    if (k0 + 3 * BK < cx.kend) fill_slot(cx, vaB, vbB, k0 + 3 * BK);
    asm volatile("s_waitcnt lgkmcnt(0)" ::: "memory");
    __builtin_amdgcn_s_barrier();
    asm volatile("" ::: "memory");

    {
      const ushort* Bsrc = cx.isdiag ? As : Bs;
#pragma unroll
      for (int kk = 0; kk < 2; ++kk) {
        const int kb = kk * 32 + (lane >> 4) * 8;
        bf16x8 a[2], b[4];
#pragma unroll
        for (int m = 0; m < 2; ++m)
          a[m] = *reinterpret_cast<const bf16x8*>(
              &As[(wr + m * 16 + (lane & 15)) * LDSS + kb]);
#pragma unroll
        for (int n = 0; n < 4; ++n)
          b[n] = *reinterpret_cast<const bf16x8*>(
              &Bsrc[(wc + n * 16 + (lane & 15)) * LDSS + kb]);
#pragma unroll
        for (int m = 0; m < 2; ++m)
#pragma unroll
          for (int n = 0; n < 4; ++n)
            acc[m][n] = __builtin_amdgcn_mfma_f32_16x16x32_bf16(a[m], b[n],
                                                                acc[m][n], 0, 0, 0);
      }
    }
  }

  // C/D layout (m89): col = lane&15, row = (lane>>4)*4 + reg. Skip mirrors.
  float* gp = Gp + (size_t)(ch * P + ks) * (NROW * NROW);
#pragma unroll
  for (int m = 0; m < 2; ++m)
#pragma unroll
    for (int n = 0; n < 4; ++n) {
      const int grow = row_base + wr + m * 16 + ((lane >> 4) << 2);
      const int gcol = col_base + wc + n * 16 + (lane & 15);
      if ((grow >> 6) > (gcol >> 6)) continue;  // lower-tri mirror: not stored
#pragma unroll
      for (int j = 0; j < 4; ++j)
        gp[(size_t)(grow + j) * NROW + gcol] = acc[m][n][j];
    }
}

// ---------------------------------------------------------------------------
__device__ __forceinline__ float block_sum256(float v, float* sm) {
#pragma unroll
  for (int o = 32; o > 0; o >>= 1) v += __shfl_down(v, o, 64);
  const int lane = threadIdx.x & 63;
  const int w = threadIdx.x >> 6;
  if (lane == 0) sm[w] = v;
  __syncthreads();
  float r = 0.f;
  if (threadIdx.x == 0) r = sm[0] + sm[1] + sm[2] + sm[3];
  __syncthreads();
  return r;  // valid on thread 0
}

// ---------------------------------------------------------------------------
// Fold K-split partials for one (ch,tile) AND produce tile sum + diag trace.
// sums layout: 20 floats/ch: [0..9] tile sums, [10..13] diag-tile traces.
__global__ __launch_bounds__(256) void foldsum_kernel(
    const f32x4* __restrict__ Gp, f32x4* __restrict__ Gf,
    float* __restrict__ sums, int P) {
  const int t = blockIdx.x;
  const int ch = blockIdx.y;
  const int ti = g_TI[t], tj = g_TJ[t];
  const bool isdiag = (ti == tj);
  const int tid = threadIdx.x;
  float s = 0.f, tr = 0.f;
#pragma unroll
  for (int i = 0; i < 4; ++i) {
    const int idx4 = tid * 4 + i;
    const int rrow = idx4 >> 4;       // 0..63
    const int c4 = idx4 & 15;         // 0..15
    const int base_v = (ti * 64 + rrow) * 64 + tj * 16 + c4;
    f32x4 v = Gp[(size_t)(ch * P) * 16384 + base_v];
    for (int p = 1; p < P; ++p) v += Gp[(size_t)(ch * P + p) * 16384 + base_v];
    Gf[(size_t)ch * 16384 + base_v] = v;
    s += (v.x + v.y) + (v.z + v.w);
    if (isdiag) {
      const int cb = c4 * 4;
#pragma unroll
      for (int e = 0; e < 4; ++e)
        if (cb + e == rrow) tr += v[e];
    }
  }
  __shared__ float sm[4];
  float sG = block_sum256(s, sm);
  float sT = block_sum256(tr, sm);
  if (tid == 0) {
    sums[ch * 20 + t] = sG;
    if (isdiag) sums[ch * 20 + 10 + ti] = sT;
  }
}

// ---------------------------------------------------------------------------
// per (tile, ch): w * sign * sum over tile of sum_a exp(-L2/(bw*2^a)).
__global__ __launch_bounds__(256) void mmd_kernel(const float* __restrict__ Gf,
                                                  const float* __restrict__ sums,
                                                  float* __restrict__ partial) {
  const int t = blockIdx.x;
  const int ch = blockIdx.y;
  const int ti = g_TI[t], tj = g_TJ[t];
  const int tid = threadIdx.x;
  const float* g = Gf + (size_t)ch * (NROW * NROW);

  // bandwidth: sum(G) = sum_diag_tiles + 2*sum_offdiag_tiles
  const float* sc = sums + ch * 20;
  float sumG = 0.f;
#pragma unroll
  for (int k = 0; k < NTILE; ++k)
    sumG += (g_TI[k] == g_TJ[k] ? 1.f : 2.f) * sc[k];
  const float trace = (sc[10] + sc[11]) + (sc[12] + sc[13]);
  const float sumL2 = 2.f * NROW * trace - 2.f * sumG;
  const float bw = sumL2 / (float)(NROW * NROW - NROW) * 0.25f;
  float inv[5];
#pragma unroll
  for (int a = 0; a < 5; ++a) inv[a] = -1.f / (bw * (float)(1 << a));

  __shared__ float dA[64], dB[64];
  if (tid < 64) dA[tid] = g[(size_t)(ti * 64 + tid) * (NROW + 1)];
  else if (tid < 128) dB[tid - 64] = g[(size_t)(tj * 64 + (tid - 64)) * (NROW + 1)];
  __syncthreads();

  const int col = tid & 63;
  const int qq = tid >> 6;
  const float dj = dB[col];
  float acc = 0.f;
#pragma unroll 4
  for (int it = 0; it < 16; ++it) {
    const int r = it * 4 + qq;
    const float L2 = dA[r] + dj - 2.f * g[(size_t)(ti * 64 + r) * NROW + tj * 64 + col];
    float kv = 0.f;
#pragma unroll
    for (int a = 0; a < 5; ++a) kv += __expf(L2 * inv[a]);
    acc += kv;
  }
  __shared__ float sm[4];
  float tot = block_sum256(acc, sm);
  if (tid == 0) {
    float w = (ti == tj) ? 1.f : 2.f;                    // off-diag mirror
    float sgn = ((ti >= 2) == (tj >= 2)) ? 1.f : -1.f;   // XX/YY + , XY/YX -
    partial[ch * NTILE + t] = tot * w * sgn;
  }
}

__global__ __launch_bounds__(256) void final_kernel(const float* __restrict__ partial,
                                                    float* __restrict__ out) {
  const int tid = threadIdx.x;
  float v = (tid < NCH * NTILE) ? partial[tid] : 0.f;
  __shared__ float sm[4];
  float tot = block_sum256(v, sm);
  if (tid == 0) out[0] = tot * (1.f / (NCH * 128.f * 128.f));
}

// ---------------------------------------------------------------------------
extern "C" void kernel_launch(void* const* d_in, const int* in_sizes, int n_in,
                              void* d_out, int out_size, void* d_ws, size_t ws_size,
                              hipStream_t stream) {
  const float* src = (const float*)d_in[0];
  const float* tgt = (const float*)d_in[1];
  float* out = (float*)d_out;
  const size_t GSZ = (size_t)NROW * NROW;  // 65536

  // P=16: grid 1008 -> ~4 blocks/CU (the 36.9KB-LDS residency cap), 4 K-iters.
  // Gp (88 MB) stays L3-resident for foldsum.
  int kshift = 0;
  if (ws_size >= (NCH * 17 * GSZ + 512) * sizeof(float)) kshift = 4;
  else if (ws_size >= (NCH * 9 * GSZ + 512) * sizeof(float)) kshift = 3;
  else if (ws_size >= (NCH * 5 * GSZ + 512) * sizeof(float)) kshift = 2;
  else if (ws_size >= (NCH * 3 * GSZ + 512) * sizeof(float)) kshift = 1;
  const int P = 1 << kshift;

  float* Gp = (float*)d_ws;
  float* Gf = (P > 1) ? Gp + (size_t)NCH * P * GSZ : Gp;  // P==1: alias, fold is copy
  float* sums = Gf + (size_t)NCH * GSZ;                   // NCH*20
  float* partial = sums + NCH * 20;                       // NCH*10

  // XCD-grouped grid: 3 pair-blocks per (ch,ks) group (bijective m204 split)
  const int NG = NCH * P;
  const int q = NG / 8, r8 = NG % 8;
  const int grid = 8 * (q + (r8 ? 1 : 0)) * 3;

  gram_kernel<<<dim3(grid), 512, 0, stream>>>(src, tgt, Gp, kshift, DIM >> kshift);
  foldsum_kernel<<<dim3(NTILE, NCH), 256, 0, stream>>>((const f32x4*)Gp,
                                                       (f32x4*)Gf, sums, P);
  mmd_kernel<<<dim3(NTILE, NCH), 256, 0, stream>>>(Gf, sums, partial);
  final_kernel<<<1, 256, 0, stream>>>(partial, out);
}

// Round 11
// 59.277 us; speedup vs baseline: 1.4106x; 1.4106x over previous
//
#include <hip/hip_runtime.h>
#include <hip/hip_bf16.h>
#include <stdint.h>

typedef __attribute__((ext_vector_type(4))) float f32x4;
typedef __attribute__((ext_vector_type(8))) short bf16x8;
typedef __attribute__((ext_vector_type(4))) uint32_t u32x4;

#define NCH 21
#define NROW 256
#define DIM 4096
#define BMP 128   // pair-merged tile dim
#define BK 64
#define LDSS 72   // row stride in ushorts: 144 B
#define SLOT (BMP * LDSS)
#define NTILE 10  // upper-triangle 64x64 tiles of the 256x256 Gram

__device__ const int g_TI[NTILE] = {0, 0, 0, 0, 1, 1, 1, 2, 2, 3};
__device__ const int g_TJ[NTILE] = {0, 1, 2, 3, 1, 2, 3, 2, 3, 3};

__device__ __forceinline__ uint32_t pack_bf2(float x, float y) {
  __hip_bfloat162 h = __float22bfloat162_rn(float2{x, y});  // v_cvt_pk_bf16_f32
  union { __hip_bfloat162 h; uint32_t u; } c;
  c.h = h;
  return c.u;
}

struct StageCtx {
  const float* ap[2];
  const float* bp[2];
  bool isdiag;
  int r0, c8;
};

__device__ __forceinline__ void fill_slot(const StageCtx& cx, f32x4 (&va)[2][2],
                                          f32x4 (&vb)[2][2], int k) {
#pragma unroll
  for (int p = 0; p < 2; ++p) {
    va[p][0] = *reinterpret_cast<const f32x4*>(cx.ap[p] + k);
    va[p][1] = *reinterpret_cast<const f32x4*>(cx.ap[p] + k + 4);
    if (!cx.isdiag) {
      vb[p][0] = *reinterpret_cast<const f32x4*>(cx.bp[p] + k);
      vb[p][1] = *reinterpret_cast<const f32x4*>(cx.bp[p] + k + 4);
    }
  }
}

__device__ __forceinline__ void stage_slot(const StageCtx& cx, ushort* As,
                                           ushort* Bs, f32x4 (&va)[2][2],
                                           f32x4 (&vb)[2][2]) {
#pragma unroll
  for (int p = 0; p < 2; ++p) {
    u32x4 wa;
    wa.x = pack_bf2(va[p][0].x, va[p][0].y);
    wa.y = pack_bf2(va[p][0].z, va[p][0].w);
    wa.z = pack_bf2(va[p][1].x, va[p][1].y);
    wa.w = pack_bf2(va[p][1].z, va[p][1].w);
    *reinterpret_cast<u32x4*>(&As[(cx.r0 + p * 64) * LDSS + cx.c8]) = wa;
    if (!cx.isdiag) {
      u32x4 wb;
      wb.x = pack_bf2(vb[p][0].x, vb[p][0].y);
      wb.y = pack_bf2(vb[p][0].z, vb[p][0].w);
      wb.z = pack_bf2(vb[p][1].x, vb[p][1].y);
      wb.w = pack_bf2(vb[p][1].z, vb[p][1].w);
      *reinterpret_cast<u32x4*>(&Bs[(cx.r0 + p * 64) * LDSS + cx.c8]) = wb;
    }
  }
}

// ---------------------------------------------------------------------------
// Pair-merged partial Gram (R9 geometry) with LDS double-buffer and ONE
// barrier per K-iter. Per iter k:
//   stage buf[(k+1)&1] <- reg-set[(k+1)&1] (loads issued at iter k-1)
//   fill  reg-set[(k+1)&1] <- K-step k+3   (use-to-issue distance = 2 iters)
//   MFMA  buf[k&1]
//   lgkmcnt(0); s_barrier                  (never vmcnt(0) in the loop)
// Write of buf[(k+1)&1] races only with reads of buf[k&1] -> safe with one
// barrier. Stage-before-fill avoids async-load WAR on the shared reg set.
// ---------------------------------------------------------------------------
__global__ __launch_bounds__(512, 4) void gram_kernel(
    const float* __restrict__ src, const float* __restrict__ tgt,
    float* __restrict__ Gp, int kshift, int kchunk) {
  const int P = 1 << kshift;
  const int NG = NCH << kshift;          // number of (ch,ks) groups
  const int q = NG >> 3, r8 = NG & 7;    // groups per XCD
  const int x = blockIdx.x & 7;          // XCD id (empirical round-robin)
  const int slot = blockIdx.x >> 3;
  const int cnt = q + (x < r8 ? 1 : 0);
  if (slot >= cnt * 3) return;           // padded grid tail (uniform exit)
  const int gbase = (x < r8) ? x * (q + 1) : r8 * (q + 1) + (x - r8) * q;
  const int gi = slot / 3;
  const int bt = slot - gi * 3;
  const int g = gbase + gi;
  const int ch = g >> kshift;
  const int ks = g & (P - 1);
  const int kbase = ks * kchunk;
  const int row_base = (bt == 1) ? 128 : 0;
  const int col_base = (bt == 0) ? 0 : 128;
  const int tid = threadIdx.x;
  const int lane = tid & 63;

  __shared__ __attribute__((aligned(16))) ushort As[2 * SLOT];
  __shared__ __attribute__((aligned(16))) ushort Bs[2 * SLOT];

  f32x4 acc[2][4];
#pragma unroll
  for (int m = 0; m < 2; ++m)
#pragma unroll
    for (int n = 0; n < 4; ++n)
      acc[m][n] = (f32x4){0.f, 0.f, 0.f, 0.f};

  const int wave = tid >> 6;          // 0..7
  const int wr = (wave >> 1) * 32;    // 0,32,64,96
  const int wc = (wave & 1) * 64;     // 0,64

  StageCtx cx;
  cx.isdiag = (bt != 2);
  cx.r0 = tid >> 3;          // 0..63
  cx.c8 = (tid & 7) * 8;     // 0,8,...,56
  {
    const float* Ab = row_base ? tgt : src;
    const float* Bb = col_base ? tgt : src;
#pragma unroll
    for (int p = 0; p < 2; ++p) {
      cx.ap[p] = Ab + ((size_t)(cx.r0 + p * 64) * NCH + ch) * DIM + cx.c8;
      cx.bp[p] = Bb + ((size_t)(cx.r0 + p * 64) * NCH + ch) * DIM + cx.c8;
    }
  }

  const int nk = kchunk / BK;  // K-iters (8 at P=8)

  // prologue: buf0 <- k0; setB <- k1; setA <- k2
  f32x4 vaA[2][2], vbA[2][2], vaB[2][2], vbB[2][2];
  fill_slot(cx, vaA, vbA, kbase);
  stage_slot(cx, As, Bs, vaA, vbA);               // vmcnt wait at use
  if (nk > 1) fill_slot(cx, vaB, vbB, kbase + BK);
  if (nk > 2) fill_slot(cx, vaA, vbA, kbase + 2 * BK);
  asm volatile("s_waitcnt lgkmcnt(0)" ::: "memory");
  __builtin_amdgcn_s_barrier();
  asm volatile("" ::: "memory");

  for (int k = 0; k < nk; ++k) {
    const int cur = k & 1;
    if (k + 1 < nk) {
      if (cur == 0) {  // next buffer/parity 1 <- setB
        stage_slot(cx, As + SLOT, Bs + SLOT, vaB, vbB);
        if (k + 3 < nk) fill_slot(cx, vaB, vbB, kbase + (k + 3) * BK);
      } else {         // next buffer/parity 0 <- setA
        stage_slot(cx, As, Bs, vaA, vbA);
        if (k + 3 < nk) fill_slot(cx, vaA, vbA, kbase + (k + 3) * BK);
      }
    }

    const ushort* Ar = As + cur * SLOT;
    const ushort* Br = (cx.isdiag ? As : Bs) + cur * SLOT;
#pragma unroll
    for (int kk = 0; kk < 2; ++kk) {
      const int kb = kk * 32 + (lane >> 4) * 8;
      bf16x8 a[2], b[4];
#pragma unroll
      for (int m = 0; m < 2; ++m)
        a[m] = *reinterpret_cast<const bf16x8*>(
            &Ar[(wr + m * 16 + (lane & 15)) * LDSS + kb]);
#pragma unroll
      for (int n = 0; n < 4; ++n)
        b[n] = *reinterpret_cast<const bf16x8*>(
            &Br[(wc + n * 16 + (lane & 15)) * LDSS + kb]);
#pragma unroll
      for (int m = 0; m < 2; ++m)
#pragma unroll
        for (int n = 0; n < 4; ++n)
          acc[m][n] = __builtin_amdgcn_mfma_f32_16x16x32_bf16(a[m], b[n],
                                                              acc[m][n], 0, 0, 0);
    }

    // single barrier per iter: stage of buf[!cur] done, reads of buf[cur] done
    asm volatile("s_waitcnt lgkmcnt(0)" ::: "memory");
    __builtin_amdgcn_s_barrier();
    asm volatile("" ::: "memory");
  }

  // C/D layout (m89): col = lane&15, row = (lane>>4)*4 + reg. Skip mirrors.
  float* gp = Gp + (size_t)(ch * P + ks) * (NROW * NROW);
#pragma unroll
  for (int m = 0; m < 2; ++m)
#pragma unroll
    for (int n = 0; n < 4; ++n) {
      const int grow = row_base + wr + m * 16 + ((lane >> 4) << 2);
      const int gcol = col_base + wc + n * 16 + (lane & 15);
      if ((grow >> 6) > (gcol >> 6)) continue;  // lower-tri mirror: not stored
#pragma unroll
      for (int j = 0; j < 4; ++j)
        gp[(size_t)(grow + j) * NROW + gcol] = acc[m][n][j];
    }
}

// ---------------------------------------------------------------------------
__device__ __forceinline__ float block_sum256(float v, float* sm) {
#pragma unroll
  for (int o = 32; o > 0; o >>= 1) v += __shfl_down(v, o, 64);
  const int lane = threadIdx.x & 63;
  const int w = threadIdx.x >> 6;
  if (lane == 0) sm[w] = v;
  __syncthreads();
  float r = 0.f;
  if (threadIdx.x == 0) r = sm[0] + sm[1] + sm[2] + sm[3];
  __syncthreads();
  return r;  // valid on thread 0
}

// ---------------------------------------------------------------------------
// Fold K-split partials for one (ch,tile) AND produce tile sum + diag trace.
// sums layout: 20 floats/ch: [0..9] tile sums, [10..13] diag-tile traces.
__global__ __launch_bounds__(256) void foldsum_kernel(
    const f32x4* __restrict__ Gp, f32x4* __restrict__ Gf,
    float* __restrict__ sums, int P) {
  const int t = blockIdx.x;
  const int ch = blockIdx.y;
  const int ti = g_TI[t], tj = g_TJ[t];
  const bool isdiag = (ti == tj);
  const int tid = threadIdx.x;
  float s = 0.f, tr = 0.f;
#pragma unroll
  for (int i = 0; i < 4; ++i) {
    const int idx4 = tid * 4 + i;
    const int rrow = idx4 >> 4;       // 0..63
    const int c4 = idx4 & 15;         // 0..15
    const int base_v = (ti * 64 + rrow) * 64 + tj * 16 + c4;
    f32x4 v = Gp[(size_t)(ch * P) * 16384 + base_v];
    for (int p = 1; p < P; ++p) v += Gp[(size_t)(ch * P + p) * 16384 + base_v];
    Gf[(size_t)ch * 16384 + base_v] = v;
    s += (v.x + v.y) + (v.z + v.w);
    if (isdiag) {
      const int cb = c4 * 4;
#pragma unroll
      for (int e = 0; e < 4; ++e)
        if (cb + e == rrow) tr += v[e];
    }
  }
  __shared__ float sm[4];
  float sG = block_sum256(s, sm);
  float sT = block_sum256(tr, sm);
  if (tid == 0) {
    sums[ch * 20 + t] = sG;
    if (isdiag) sums[ch * 20 + 10 + ti] = sT;
  }
}

// ---------------------------------------------------------------------------
// per (tile, ch): w * sign * sum over tile of sum_a exp(-L2/(bw*2^a)).
__global__ __launch_bounds__(256) void mmd_kernel(const float* __restrict__ Gf,
                                                  const float* __restrict__ sums,
                                                  float* __restrict__ partial) {
  const int t = blockIdx.x;
  const int ch = blockIdx.y;
  const int ti = g_TI[t], tj = g_TJ[t];
  const int tid = threadIdx.x;
  const float* g = Gf + (size_t)ch * (NROW * NROW);

  // bandwidth: sum(G) = sum_diag_tiles + 2*sum_offdiag_tiles
  const float* sc = sums + ch * 20;
  float sumG = 0.f;
#pragma unroll
  for (int k = 0; k < NTILE; ++k)
    sumG += (g_TI[k] == g_TJ[k] ? 1.f : 2.f) * sc[k];
  const float trace = (sc[10] + sc[11]) + (sc[12] + sc[13]);
  const float sumL2 = 2.f * NROW * trace - 2.f * sumG;
  const float bw = sumL2 / (float)(NROW * NROW - NROW) * 0.25f;
  float inv[5];
#pragma unroll
  for (int a = 0; a < 5; ++a) inv[a] = -1.f / (bw * (float)(1 << a));

  __shared__ float dA[64], dB[64];
  if (tid < 64) dA[tid] = g[(size_t)(ti * 64 + tid) * (NROW + 1)];
  else if (tid < 128) dB[tid - 64] = g[(size_t)(tj * 64 + (tid - 64)) * (NROW + 1)];
  __syncthreads();

  const int col = tid & 63;
  const int qq = tid >> 6;
  const float dj = dB[col];
  float acc = 0.f;
#pragma unroll 4
  for (int it = 0; it < 16; ++it) {
    const int r = it * 4 + qq;
    const float L2 = dA[r] + dj - 2.f * g[(size_t)(ti * 64 + r) * NROW + tj * 64 + col];
    float kv = 0.f;
#pragma unroll
    for (int a = 0; a < 5; ++a) kv += __expf(L2 * inv[a]);
    acc += kv;
  }
  __shared__ float sm[4];
  float tot = block_sum256(acc, sm);
  if (tid == 0) {
    float w = (ti == tj) ? 1.f : 2.f;                    // off-diag mirror
    float sgn = ((ti >= 2) == (tj >= 2)) ? 1.f : -1.f;   // XX/YY + , XY/YX -
    partial[ch * NTILE + t] = tot * w * sgn;
  }
}

__global__ __launch_bounds__(256) void final_kernel(const float* __restrict__ partial,
                                                    float* __restrict__ out) {
  const int tid = threadIdx.x;
  float v = (tid < NCH * NTILE) ? partial[tid] : 0.f;
  __shared__ float sm[4];
  float tot = block_sum256(v, sm);
  if (tid == 0) out[0] = tot * (1.f / (NCH * 128.f * 128.f));
}

// ---------------------------------------------------------------------------
extern "C" void kernel_launch(void* const* d_in, const int* in_sizes, int n_in,
                              void* d_out, int out_size, void* d_ws, size_t ws_size,
                              hipStream_t stream) {
  const float* src = (const float*)d_in[0];
  const float* tgt = (const float*)d_in[1];
  float* out = (float*)d_out;
  const size_t GSZ = (size_t)NROW * NROW;  // 65536

  // P capped at 8: P=16 made foldsum read 107 MB at 2.6 TB/s (R10, 44 us).
  int kshift = 0;
  if (ws_size >= (NCH * 9 * GSZ + 512) * sizeof(float)) kshift = 3;
  else if (ws_size >= (NCH * 5 * GSZ + 512) * sizeof(float)) kshift = 2;
  else if (ws_size >= (NCH * 3 * GSZ + 512) * sizeof(float)) kshift = 1;
  const int P = 1 << kshift;

  float* Gp = (float*)d_ws;
  float* Gf = (P > 1) ? Gp + (size_t)NCH * P * GSZ : Gp;  // P==1: alias, fold is copy
  float* sums = Gf + (size_t)NCH * GSZ;                   // NCH*20
  float* partial = sums + NCH * 20;                       // NCH*10

  // XCD-grouped grid: 3 pair-blocks per (ch,ks) group (bijective m204 split)
  const int NG = NCH * P;
  const int q = NG / 8, r8 = NG % 8;
  const int grid = 8 * (q + (r8 ? 1 : 0)) * 3;

  gram_kernel<<<dim3(grid), 512, 0, stream>>>(src, tgt, Gp, kshift, DIM >> kshift);
  foldsum_kernel<<<dim3(NTILE, NCH), 256, 0, stream>>>((const f32x4*)Gp,
                                                       (f32x4*)Gf, sums, P);
  mmd_kernel<<<dim3(NTILE, NCH), 256, 0, stream>>>(Gf, sums, partial);
  final_kernel<<<1, 256, 0, stream>>>(partial, out);
}